// Round 1
// baseline (862.717 us; speedup 1.0000x reference)
//
#include <hip/hip_runtime.h>
#include <math.h>

// EvolutionBank: fused circular-buffer write + temporal consistency.
// bank: (1e6, 6, 32) f32, emb: (B,32) f32, idx: (B,) i32, ptr: (1e6,) i32.
// out: (B,) f32 consistency. The scatter bank[idx, ptr[idx]%6] = emb never
// needs to materialize: we substitute the row in registers during the gather.

#define W 6
#define D 32
#define EPS 1e-6f
#define NODES_PER_BLOCK 8   // 256 threads / 32 lanes-per-node

__global__ __launch_bounds__(256) void evo_consistency_kernel(
    const float* __restrict__ bank,
    const float* __restrict__ emb,
    const int*   __restrict__ idx,
    const int*   __restrict__ ptr,
    float*       __restrict__ out,
    int B)
{
    const int grp = blockIdx.x * NODES_PER_BLOCK + (threadIdx.x >> 5);
    const int d   = threadIdx.x & 31;          // lane within 32-lane group = dim
    if (grp >= B) return;

    const int node = idx[grp];
    const int p    = ((unsigned)ptr[node]) % W;   // slot being overwritten
    const float e  = emb[(size_t)grp * D + d];

    const float* base = bank + (size_t)node * (W * D);

    // Gather the 6 window rows; row p comes from emb (skip its HBM fetch —
    // p is uniform across the 32-lane group, so this branch is half-wave
    // uniform and the skipped row is a full aligned 128B line).
    float r[W];
    #pragma unroll
    for (int w = 0; w < W; ++w) {
        if (w == p) r[w] = e;
        else        r[w] = base[w * D + d];
    }

    // Normalize each row: r[w] /= max(||r[w]||, eps).
    // Butterfly reduce over the 32-lane group (xor masks <=16 stay within
    // each half of the wave64).
    #pragma unroll
    for (int w = 0; w < W; ++w) {
        float ss = r[w] * r[w];
        #pragma unroll
        for (int m = 16; m >= 1; m >>= 1) ss += __shfl_xor(ss, m, 64);
        const float inv = 1.0f / fmaxf(sqrtf(ss), EPS);
        r[w] *= inv;
    }

    // Adjacent cosine similarities (rows already unit-normalized).
    float sim[W - 1];
    #pragma unroll
    for (int w = 0; w < W - 1; ++w) {
        float s = r[w] * r[w + 1];
        #pragma unroll
        for (int m = 16; m >= 1; m >>= 1) s += __shfl_xor(s, m, 64);
        sim[w] = s;   // every lane holds the full value after the butterfly
    }

    // Unbiased std over the 5 sims (ddof=1 -> divide by 4), then 1/(1+std).
    float mean = 0.f;
    #pragma unroll
    for (int w = 0; w < W - 1; ++w) mean += sim[w];
    mean *= (1.0f / (W - 1));
    float var = 0.f;
    #pragma unroll
    for (int w = 0; w < W - 1; ++w) { const float t = sim[w] - mean; var += t * t; }
    var *= (1.0f / (W - 2));

    float c = 1.0f / (1.0f + sqrtf(var));
    c = fminf(fmaxf(c, 0.0f), 1.0f);

    if (d == 0) out[grp] = c;
}

extern "C" void kernel_launch(void* const* d_in, const int* in_sizes, int n_in,
                              void* d_out, int out_size, void* d_ws, size_t ws_size,
                              hipStream_t stream) {
    const float* bank = (const float*)d_in[0];
    const float* emb  = (const float*)d_in[1];
    const int*   idx  = (const int*)d_in[2];
    const int*   ptr  = (const int*)d_in[3];
    // d_in[4] = filled: unused by the returned output.
    float* out = (float*)d_out;

    const int B = in_sizes[2];                 // idx has B elements
    const int blocks = (B + NODES_PER_BLOCK - 1) / NODES_PER_BLOCK;
    evo_consistency_kernel<<<blocks, 256, 0, stream>>>(bank, emb, idx, ptr, out, B);
}

// Round 2
// 850.956 us; speedup vs baseline: 1.0138x; 1.0138x over previous
//
#include <hip/hip_runtime.h>
#include <math.h>

// EvolutionBank: fused circular-buffer write + temporal consistency.
// bank: (1e6, 6, 32) f32, emb: (B,32) f32, idx: (B,) i32, ptr: (1e6,) i32.
// out: (B,) f32 consistency. The scatter bank[idx, ptr[idx]%6] = emb is
// fused: row p is substituted from emb in registers during the gather, so
// neither the bank write nor row p's fetch ever touches HBM.
//
// Layout: 8 lanes per node, float4 per lane (32 dims). Row load = 8 x 16 B
// = one coalesced 128 B line. Reductions: 3 in-thread adds + 3 butterfly
// shuffles within the 8-lane group (masks 1/2/4 stay inside the group).

#define W 6
#define D 32
#define EPS 1e-6f
#define LPN 8               // lanes per node
#define NODES_PER_BLOCK 32  // 256 threads / 8 lanes-per-node

__global__ __launch_bounds__(256) void evo_consistency_kernel(
    const float* __restrict__ bank,
    const float* __restrict__ emb,
    const int*   __restrict__ idx,
    const int*   __restrict__ ptr,
    float*       __restrict__ out,
    int B)
{
    const int grp = blockIdx.x * NODES_PER_BLOCK + (threadIdx.x >> 3);
    const int sub = threadIdx.x & (LPN - 1);   // which float4 of the row
    if (grp >= B) return;

    const int node   = idx[grp];
    const unsigned p = ((unsigned)ptr[node]) % W;   // slot being overwritten

    const float4* __restrict__ base = (const float4*)(bank + (size_t)node * (W * D));
    const float4 e = ((const float4*)(emb + (size_t)grp * D))[sub];

    // Gather 6 rows; row p comes from emb (its 128 B line is never fetched —
    // p is uniform across the 8-lane group, so the masked-off load skips the
    // whole line for that group).
    float4 r[W];
    #pragma unroll
    for (int w = 0; w < W; ++w) {
        if ((unsigned)w == p) r[w] = e;
        else                  r[w] = base[w * (D / 4) + sub];
    }

    // Normalize each row: r[w] /= max(||r[w]||, eps).
    #pragma unroll
    for (int w = 0; w < W; ++w) {
        float ss = r[w].x * r[w].x + r[w].y * r[w].y
                 + r[w].z * r[w].z + r[w].w * r[w].w;
        ss += __shfl_xor(ss, 1, 64);
        ss += __shfl_xor(ss, 2, 64);
        ss += __shfl_xor(ss, 4, 64);
        const float inv = 1.0f / fmaxf(sqrtf(ss), EPS);
        r[w].x *= inv; r[w].y *= inv; r[w].z *= inv; r[w].w *= inv;
    }

    // Adjacent cosine similarities (rows already unit-normalized).
    float sim[W - 1];
    #pragma unroll
    for (int w = 0; w < W - 1; ++w) {
        float s = r[w].x * r[w + 1].x + r[w].y * r[w + 1].y
                + r[w].z * r[w + 1].z + r[w].w * r[w + 1].w;
        s += __shfl_xor(s, 1, 64);
        s += __shfl_xor(s, 2, 64);
        s += __shfl_xor(s, 4, 64);
        sim[w] = s;   // all 8 lanes of the group hold the full dot product
    }

    // Unbiased std over the 5 sims (ddof=1 -> /4), then clip(1/(1+std),0,1).
    float mean = 0.f;
    #pragma unroll
    for (int w = 0; w < W - 1; ++w) mean += sim[w];
    mean *= (1.0f / (W - 1));
    float var = 0.f;
    #pragma unroll
    for (int w = 0; w < W - 1; ++w) { const float t = sim[w] - mean; var += t * t; }
    var *= (1.0f / (W - 2));

    float c = 1.0f / (1.0f + sqrtf(var));
    c = fminf(fmaxf(c, 0.0f), 1.0f);

    if (sub == 0) out[grp] = c;
}

extern "C" void kernel_launch(void* const* d_in, const int* in_sizes, int n_in,
                              void* d_out, int out_size, void* d_ws, size_t ws_size,
                              hipStream_t stream) {
    const float* bank = (const float*)d_in[0];
    const float* emb  = (const float*)d_in[1];
    const int*   idx  = (const int*)d_in[2];
    const int*   ptr  = (const int*)d_in[3];
    // d_in[4] = filled: does not affect the returned output.
    float* out = (float*)d_out;

    const int B = in_sizes[2];                 // idx has B elements
    const int blocks = (B + NODES_PER_BLOCK - 1) / NODES_PER_BLOCK;
    evo_consistency_kernel<<<blocks, 256, 0, stream>>>(bank, emb, idx, ptr, out, B);
}